// Round 1
// baseline (154.634 us; speedup 1.0000x reference)
//
#include <hip/hip_runtime.h>

#define NC 19
#define NB (NC * NC)      // 361 joint-histogram bins
#define EPS 1e-5f

// Kernel 1: joint histogram J[t*19+p] over all element pairs.
// Per-wave privatized LDS copies (4 waves * 361 bins), int4 vector loads.
__global__ __launch_bounds__(256) void joint_hist_kernel(
    const int4* __restrict__ yp, const int4* __restrict__ yt,
    unsigned int* __restrict__ gJ, int n4)
{
    __shared__ unsigned int sJ[4 * NB];
    const int tid = threadIdx.x;
    unsigned int* mine = &sJ[(tid >> 6) * NB];   // one copy per wave

    for (int i = tid; i < 4 * NB; i += 256) sJ[i] = 0u;
    __syncthreads();

    const int stride = gridDim.x * 256;
    for (int i = blockIdx.x * 256 + tid; i < n4; i += stride) {
        int4 p = yp[i];
        int4 t = yt[i];
        atomicAdd(&mine[t.x * NC + p.x], 1u);
        atomicAdd(&mine[t.y * NC + p.y], 1u);
        atomicAdd(&mine[t.z * NC + p.z], 1u);
        atomicAdd(&mine[t.w * NC + p.w], 1u);
    }
    __syncthreads();

    // Reduce the 4 wave-copies, one device atomic per bin per block.
    for (int i = tid; i < NB; i += 256) {
        unsigned int v = sJ[i] + sJ[NB + i] + sJ[2 * NB + i] + sJ[3 * NB + i];
        if (v) atomicAdd(&gJ[i], v);
    }
}

// Kernel 2: one wave. Lane c (<19) computes dice for class c from the joint
// histogram: inter = J[c][c], count_y = row sum, count_p = col sum.
__global__ __launch_bounds__(64) void dice_final_kernel(
    const unsigned int* __restrict__ gJ, float* __restrict__ out)
{
    const int lane = threadIdx.x;
    float dice = 0.0f;
    if (lane < NC) {
        float inter = (float)gJ[lane * NC + lane];
        float cy = 0.0f, cp = 0.0f;
        #pragma unroll
        for (int j = 0; j < NC; ++j) {
            cy += (float)gJ[lane * NC + j];
            cp += (float)gJ[j * NC + lane];
        }
        float uni = cy + cp - inter;
        dice = (2.0f * inter + EPS) / (uni + EPS);
    }
    // 64-lane shuffle reduction (lanes >= 19 contribute 0)
    #pragma unroll
    for (int off = 32; off > 0; off >>= 1)
        dice += __shfl_down(dice, off, 64);
    if (lane == 0) out[0] = 1.0f - dice / (float)NC;
}

extern "C" void kernel_launch(void* const* d_in, const int* in_sizes, int n_in,
                              void* d_out, int out_size, void* d_ws, size_t ws_size,
                              hipStream_t stream)
{
    const int4* yp = (const int4*)d_in[0];   // y_pred, int32
    const int4* yt = (const int4*)d_in[1];   // y,      int32
    unsigned int* gJ = (unsigned int*)d_ws;  // 361 u32 counters
    float* out = (float*)d_out;

    const int n = in_sizes[0];               // 16*1024*1024, divisible by 4
    const int n4 = n >> 2;

    // ws is poisoned to 0xAA before every timed launch — zero the counters.
    hipMemsetAsync(d_ws, 0, NB * sizeof(unsigned int), stream);

    const int grid = 1024;                   // 4 blocks/CU, 16 waves/CU
    joint_hist_kernel<<<grid, 256, 0, stream>>>(yp, yt, gJ, n4);
    dice_final_kernel<<<1, 64, 0, stream>>>(gJ, out);
}